// Round 1
// baseline (278.616 us; speedup 1.0000x reference)
//
#include <hip/hip_runtime.h>

// ---------------- helpers ----------------

__device__ __forceinline__ float ldf(const void* p, long long i, int f32) {
    if (f32) return ((const float*)p)[i];
    unsigned int u = ((const unsigned short*)p)[i];
    return __uint_as_float(u << 16);
}
__device__ __forceinline__ float bfl(unsigned int u) { return __uint_as_float(u << 16); }
__device__ __forceinline__ float bfh(unsigned int u) { return __uint_as_float(u & 0xFFFF0000u); }
__device__ __forceinline__ int ld_idx(const int* p, long long i, int i64) {
    return i64 ? p[2 * i] : p[i];   // little-endian low word of int64
}
__device__ __forceinline__ unsigned short f2bf(float v) {
    unsigned int x = __float_as_uint(v);
    return (unsigned short)((x + 0x7FFFu + ((x >> 16) & 1u)) >> 16);  // RNE
}
__device__ __forceinline__ int clampi(int v, int lo, int hi) {
    return v < lo ? lo : (v > hi ? hi : v);
}

// ---------------- weights layout (contiguous f32) ----------------
#define OW1 0
#define OB1 8192
#define OW2 8320
#define OB2 24704
#define OW3 24832
#define OB3 41216
#define OW4 41344
#define OB4 49536
#define OTOT 49600

// ---------------- prep: dtype-detect + zero-init + weight convert ----------------
// flags[0]=1 f32 floats / 0 bf16 ; flags[1]=1 int64 / 0 int32

__global__ void gnn_prep(const void* W1, const void* b1, const void* W2, const void* b2,
                         const void* W3, const void* b3, const void* W4, const void* b4,
                         const int* __restrict__ ei,
                         int* __restrict__ flags_out,
                         int* __restrict__ degcnt, float* __restrict__ pooled,
                         float* __restrict__ wsW, int N, int B) {
    __shared__ int s_cnt, s_or;
    const int t = threadIdx.x;
    if (t == 0) { s_cnt = 0; s_or = 0; }
    __syncthreads();
    {
        const unsigned int* w1w = (const unsigned int*)W1;
        int c = 0, o = 0;
        for (int i = t; i < 512; i += 256) {
            unsigned int e = (w1w[i] >> 7) & 0xFFu;
            if (e >= 100 && e <= 140) c++;
        }
        for (int i = t; i < 1024; i += 256) o |= ei[2 * i + 1];
        atomicAdd(&s_cnt, c);
        atomicOr(&s_or, o);
    }
    __syncthreads();
    const int f32 = (s_cnt > 256) ? 0 : 1;
    if (blockIdx.x == 0 && t == 0) {
        flags_out[0] = f32;
        flags_out[1] = (s_or == 0) ? 1 : 0;
    }
    const int i = blockIdx.x * 256 + t;
    const int stride = gridDim.x * 256;
    for (int j = i; j < N; j += stride) degcnt[j] = 0;
    for (int j = i; j < B * 128; j += stride) pooled[j] = 0.f;
    for (int j = i; j < OTOT; j += stride) {
        float v;
        if      (j < OB1) v = ldf(W1, j - OW1, f32);
        else if (j < OW2) v = ldf(b1, j - OB1, f32);
        else if (j < OB2) v = ldf(W2, j - OW2, f32);
        else if (j < OW3) v = ldf(b2, j - OB2, f32);
        else if (j < OB3) v = ldf(W3, j - OW3, f32);
        else if (j < OW4) v = ldf(b3, j - OB3, f32);
        else if (j < OB4) v = ldf(W4, j - OW4, f32);
        else              v = ldf(b4, j - OB4, f32);
        wsW[j] = v;
    }
}

// ---------------- CSR build ----------------

__global__ void gnn_hist(const int* __restrict__ ei, int E, int N,
                         const int* __restrict__ flags, int* __restrict__ degcnt,
                         int* __restrict__ rank) {
    int base = (blockIdx.x * 256 + threadIdx.x) * 4;
    if (base >= E) return;
    int i64 = flags[1];
    int m = min(4, E - base);
    int d[4], r[4];
#pragma unroll
    for (int j = 0; j < 4; ++j)
        if (j < m) d[j] = clampi(ld_idx(ei, (long long)E + base + j, i64), 0, N - 1);
#pragma unroll
    for (int j = 0; j < 4; ++j)
        if (j < m) r[j] = atomicAdd(&degcnt[d[j]], 1);
#pragma unroll
    for (int j = 0; j < 4; ++j)
        if (j < m) rank[base + j] = r[j];
}

__global__ void gnn_scan1(const int* __restrict__ cnt, int* __restrict__ excl,
                          int* __restrict__ sums, float* __restrict__ dis, int N) {
    __shared__ int sh[256];
    int t = threadIdx.x;
    int i = blockIdx.x * 256 + t;
    int v = (i < N) ? cnt[i] : 0;
    sh[t] = v;
    __syncthreads();
    for (int off = 1; off < 256; off <<= 1) {
        int a = (t >= off) ? sh[t - off] : 0;
        __syncthreads();
        sh[t] += a;
        __syncthreads();
    }
    if (i < N) {
        excl[i] = sh[t] - v;
        dis[i] = rsqrtf((float)v + 1.0f);
    }
    if (t == 255) sums[blockIdx.x] = sh[255];
}

__global__ void gnn_scan2(int* __restrict__ sums, int nb) {
    __shared__ int sh[256];
    int t = threadIdx.x;
    int v = (t < nb) ? sums[t] : 0;
    sh[t] = v;
    __syncthreads();
    for (int off = 1; off < 256; off <<= 1) {
        int a = (t >= off) ? sh[t - off] : 0;
        __syncthreads();
        sh[t] += a;
        __syncthreads();
    }
    if (t < nb) sums[t] = sh[t] - v;
}

// fill: scatter src ids into CSR, and build dis-prescaled bf16 x table
//   xb[n][f] = bf16( x[n][f] * dis[n] )
template <bool SMALLN>
__global__ void gnn_fill(const int* __restrict__ ei, const int* __restrict__ excl,
                         const int* __restrict__ bsums, const int* __restrict__ rank,
                         void* __restrict__ csr, int E, int N,
                         const int* __restrict__ flags,
                         const void* __restrict__ x, const float* __restrict__ dis,
                         unsigned short* __restrict__ xb) {
    const int tid = blockIdx.x * 256 + threadIdx.x;
    const int i64 = flags[1];
    if (tid < E) {
        int s = clampi(ld_idx(ei, (long long)tid, i64), 0, N - 1);
        int d = clampi(ld_idx(ei, (long long)E + tid, i64), 0, N - 1);
        int pos = excl[d] + bsums[d >> 8] + rank[tid];
        if (SMALLN) ((unsigned short*)csr)[pos] = (unsigned short)s;
        else        ((int*)csr)[pos] = s;
    }
    const int f32 = flags[0];
    const int total = N * 16;                    // groups of 4 features
    const int stride = gridDim.x * 256;
    for (int j = tid; j < total; j += stride) {
        int n = j >> 4;
        float dn = dis[n];
        float v0, v1, v2, v3;
        if (f32) {
            float4 xv = ((const float4*)x)[j];
            v0 = xv.x; v1 = xv.y; v2 = xv.z; v3 = xv.w;
        } else {
            ushort4 xv = ((const ushort4*)x)[j];
            v0 = bfl(xv.x); v1 = bfl(xv.y); v2 = bfl(xv.z); v3 = bfl(xv.w);
        }
        ushort4 o;
        o.x = f2bf(v0 * dn); o.y = f2bf(v1 * dn);
        o.z = f2bf(v2 * dn); o.w = f2bf(v3 * dn);
        ((ushort4*)xb)[j] = o;
    }
}

template <bool SMALLN>
__device__ __forceinline__ int csr_at(const void* csr, int e) {
    return SMALLN ? (int)((const unsigned short*)csr)[e] : ((const int*)csr)[e];
}

// ---------------- fused layer 1: aggX (wave-per-node) then X@W1+b1 -> relu -> H1 ------
// 16 nodes/block, 128 threads = 2 waves. Phase A: 8 passes, one wave per node,
// lanes = 8 edge-slots x 8 feature-groups (uint4 = 8 bf16 each), shfl-xor fold.
// Rows in xb are PRE-SCALED by dis[src]; final multiply by dis[n] once.

template <bool SMALLN>
__global__ __launch_bounds__(128) void gnn_aggx_lin1(const unsigned short* __restrict__ xb,
                                                     const int* __restrict__ excl,
                                                     const int* __restrict__ bsums,
                                                     const void* __restrict__ csr,
                                                     const float* __restrict__ dis,
                                                     const float* __restrict__ Wf,
                                                     const float* __restrict__ bias,
                                                     int N, int E, float* __restrict__ out) {
    __shared__ float Xs[16 * 64];   // 4 KB
    const int t = threadIdx.x;
    const int nbase = blockIdx.x * 16;
    const int wave = t >> 6;
    const int lane = t & 63;
    const int eslot = lane >> 3;    // 0..7 edge slot
    const int fg = lane & 7;        // 0..7 feature group (8 bf16 each)

    for (int pass = 0; pass < 8; ++pass) {
        const int ln = pass * 2 + wave;
        const int n = nbase + ln;
        float a0 = 0.f, a1 = 0.f, a2 = 0.f, a3 = 0.f;
        float a4 = 0.f, a5 = 0.f, a6 = 0.f, a7 = 0.f;
        if (n < N) {
            int beg = excl[n] + bsums[n >> 8];
            int end = (n + 1 < N) ? (excl[n + 1] + bsums[(n + 1) >> 8]) : E;
            for (int e = beg + eslot; e < end; e += 8) {
                int s = csr_at<SMALLN>(csr, e);
                uint4 u = *(const uint4*)(xb + (long long)s * 64 + fg * 8);
                a0 += bfl(u.x); a1 += bfh(u.x);
                a2 += bfl(u.y); a3 += bfh(u.y);
                a4 += bfl(u.z); a5 += bfh(u.z);
                a6 += bfl(u.w); a7 += bfh(u.w);
            }
        }
#pragma unroll
        for (int m = 8; m <= 32; m <<= 1) {
            a0 += __shfl_xor(a0, m); a1 += __shfl_xor(a1, m);
            a2 += __shfl_xor(a2, m); a3 += __shfl_xor(a3, m);
            a4 += __shfl_xor(a4, m); a5 += __shfl_xor(a5, m);
            a6 += __shfl_xor(a6, m); a7 += __shfl_xor(a7, m);
        }
        if (n < N && eslot == 0) {
            float dn = dis[n];
            uint4 u = *(const uint4*)(xb + (long long)n * 64 + fg * 8);  // self (prescaled)
            float4 o0, o1;
            o0.x = (a0 + bfl(u.x)) * dn; o0.y = (a1 + bfh(u.x)) * dn;
            o0.z = (a2 + bfl(u.y)) * dn; o0.w = (a3 + bfh(u.y)) * dn;
            o1.x = (a4 + bfl(u.z)) * dn; o1.y = (a5 + bfh(u.z)) * dn;
            o1.z = (a6 + bfl(u.w)) * dn; o1.w = (a7 + bfh(u.w)) * dn;
            *(float4*)&Xs[ln * 64 + fg * 8]     = o0;
            *(float4*)&Xs[ln * 64 + fg * 8 + 4] = o1;
        }
    }
    __syncthreads();

    const int fgB = t & 31, ng = t >> 5;          // ng 0..3 -> nodes ng*4..ng*4+3
    const int f0 = fgB * 4, n0 = ng * 4;
    const float4* Xs4 = (const float4*)Xs;       // [node][16]
    const float4* Wp  = (const float4*)Wf;       // [k][32]
    float4 acc[4];
#pragma unroll
    for (int j = 0; j < 4; ++j) acc[j] = make_float4(0.f, 0.f, 0.f, 0.f);
#pragma unroll 4
    for (int k4 = 0; k4 < 16; ++k4) {
        const float4 wa = Wp[(4 * k4 + 0) * 32 + fgB];
        const float4 wb = Wp[(4 * k4 + 1) * 32 + fgB];
        const float4 wc = Wp[(4 * k4 + 2) * 32 + fgB];
        const float4 wd = Wp[(4 * k4 + 3) * 32 + fgB];
#pragma unroll
        for (int j = 0; j < 4; ++j) {
            const float4 xv = Xs4[(n0 + j) * 16 + k4];
            acc[j].x = fmaf(xv.x, wa.x, acc[j].x); acc[j].y = fmaf(xv.x, wa.y, acc[j].y);
            acc[j].z = fmaf(xv.x, wa.z, acc[j].z); acc[j].w = fmaf(xv.x, wa.w, acc[j].w);
            acc[j].x = fmaf(xv.y, wb.x, acc[j].x); acc[j].y = fmaf(xv.y, wb.y, acc[j].y);
            acc[j].z = fmaf(xv.y, wb.z, acc[j].z); acc[j].w = fmaf(xv.y, wb.w, acc[j].w);
            acc[j].x = fmaf(xv.z, wc.x, acc[j].x); acc[j].y = fmaf(xv.z, wc.y, acc[j].y);
            acc[j].z = fmaf(xv.z, wc.z, acc[j].z); acc[j].w = fmaf(xv.z, wc.w, acc[j].w);
            acc[j].x = fmaf(xv.w, wd.x, acc[j].x); acc[j].y = fmaf(xv.w, wd.y, acc[j].y);
            acc[j].z = fmaf(xv.w, wd.z, acc[j].z); acc[j].w = fmaf(xv.w, wd.w, acc[j].w);
        }
    }
    const float4 b = *(const float4*)&bias[f0];
#pragma unroll
    for (int j = 0; j < 4; ++j) {
        int n = nbase + n0 + j;
        if (n >= N) continue;
        float4 a = acc[j];
        a.x = fmaxf(a.x + b.x, 0.f);
        a.y = fmaxf(a.y + b.y, 0.f);
        a.z = fmaxf(a.z + b.z, 0.f);
        a.w = fmaxf(a.w + b.w, 0.f);
        *(float4*)(out + (long long)n * 128 + f0) = a;
    }
}

// ---------------- Linear (layer 2): A2 = (H1 @ W2) * dis[n]  (bf16 out) ----------------

template <int K, bool RELU, bool OUTBF>
__global__ __launch_bounds__(128) void gnn_linear(const float* __restrict__ X,
                                                  const float* __restrict__ Wf,
                                                  const float* __restrict__ bias,
                                                  const float* __restrict__ dis,
                                                  int N, void* __restrict__ out) {
    __shared__ float Xs[16 * K];
    const int t = threadIdx.x;
    const int nbase = blockIdx.x * 16;

#pragma unroll
    for (int it = 0; it < K / 32; ++it) {
        int i4 = t + it * 128;
        int n = nbase + (i4 * 4) / K;
        float4 v = make_float4(0.f, 0.f, 0.f, 0.f);
        if (n < N) v = ((const float4*)X)[(long long)nbase * (K / 4) + i4];
        ((float4*)Xs)[i4] = v;
    }
    __syncthreads();

    const int fg = t & 31, ng = t >> 5;
    const int f0 = fg * 4, n0 = ng * 4;
    const float4* Xs4 = (const float4*)Xs;            // [node][K/4]
    const float4* Wp  = (const float4*)Wf;            // [k][32]
    float4 acc[4];
#pragma unroll
    for (int j = 0; j < 4; ++j) acc[j] = make_float4(0.f, 0.f, 0.f, 0.f);
#pragma unroll 4
    for (int k4 = 0; k4 < K / 4; ++k4) {
        const float4 wa = Wp[(4 * k4 + 0) * 32 + fg];
        const float4 wb = Wp[(4 * k4 + 1) * 32 + fg];
        const float4 wc = Wp[(4 * k4 + 2) * 32 + fg];
        const float4 wd = Wp[(4 * k4 + 3) * 32 + fg];
#pragma unroll
        for (int j = 0; j < 4; ++j) {
            const float4 xv = Xs4[(n0 + j) * (K / 4) + k4];
            acc[j].x = fmaf(xv.x, wa.x, acc[j].x); acc[j].y = fmaf(xv.x, wa.y, acc[j].y);
            acc[j].z = fmaf(xv.x, wa.z, acc[j].z); acc[j].w = fmaf(xv.x, wa.w, acc[j].w);
            acc[j].x = fmaf(xv.y, wb.x, acc[j].x); acc[j].y = fmaf(xv.y, wb.y, acc[j].y);
            acc[j].z = fmaf(xv.y, wb.z, acc[j].z); acc[j].w = fmaf(xv.y, wb.w, acc[j].w);
            acc[j].x = fmaf(xv.z, wc.x, acc[j].x); acc[j].y = fmaf(xv.z, wc.y, acc[j].y);
            acc[j].z = fmaf(xv.z, wc.z, acc[j].z); acc[j].w = fmaf(xv.z, wc.w, acc[j].w);
            acc[j].x = fmaf(xv.w, wd.x, acc[j].x); acc[j].y = fmaf(xv.w, wd.y, acc[j].y);
            acc[j].z = fmaf(xv.w, wd.z, acc[j].z); acc[j].w = fmaf(xv.w, wd.w, acc[j].w);
        }
    }
#pragma unroll
    for (int j = 0; j < 4; ++j) {
        int n = nbase + n0 + j;
        if (n >= N) continue;
        float4 a = acc[j];
        if (RELU) {
            const float4 b = *(const float4*)&bias[f0];
            a.x = fmaxf(a.x + b.x, 0.f);
            a.y = fmaxf(a.y + b.y, 0.f);
            a.z = fmaxf(a.z + b.z, 0.f);
            a.w = fmaxf(a.w + b.w, 0.f);
        }
        if (OUTBF) {
            const float dn = dis[n];
            a.x *= dn; a.y *= dn; a.z *= dn; a.w *= dn;
            uint2 u;
            u.x = (unsigned int)f2bf(a.x) | ((unsigned int)f2bf(a.y) << 16);
            u.y = (unsigned int)f2bf(a.z) | ((unsigned int)f2bf(a.w) << 16);
            *(uint2*)((unsigned short*)out + (long long)n * 128 + f0) = u;
        } else {
            *(float4*)((float*)out + (long long)n * 128 + f0) = a;
        }
    }
}

// ---------------- Layer-2 aggregation over prescaled bf16 rows -> C2 (f32) -------------
// One wave per node: lanes = 4 edge-slots x 16 feature-groups (uint4 = 8 bf16 each).

template <bool SMALLN>
__global__ __launch_bounds__(256) void gnn_agg_bf(const unsigned short* __restrict__ A2,
                                                  const int* __restrict__ excl,
                                                  const int* __restrict__ bsums,
                                                  const void* __restrict__ csr,
                                                  const float* __restrict__ dis,
                                                  const float* __restrict__ bias,
                                                  float* __restrict__ outC, int N, int E) {
    const int t = threadIdx.x;
    const int lane = t & 63;
    const int n = blockIdx.x * 4 + (t >> 6);
    if (n >= N) return;
    const int eslot = lane >> 4;       // 0..3
    const int fg = lane & 15;          // 0..15, 8 bf16 each
    float a0 = 0.f, a1 = 0.f, a2 = 0.f, a3 = 0.f;
    float a4 = 0.f, a5 = 0.f, a6 = 0.f, a7 = 0.f;
    int beg = excl[n] + bsums[n >> 8];
    int end = (n + 1 < N) ? (excl[n + 1] + bsums[(n + 1) >> 8]) : E;
    for (int e = beg + eslot; e < end; e += 4) {
        int s = csr_at<SMALLN>(csr, e);
        uint4 u = *(const uint4*)(A2 + (long long)s * 128 + fg * 8);
        a0 += bfl(u.x); a1 += bfh(u.x);
        a2 += bfl(u.y); a3 += bfh(u.y);
        a4 += bfl(u.z); a5 += bfh(u.z);
        a6 += bfl(u.w); a7 += bfh(u.w);
    }
#pragma unroll
    for (int m = 16; m <= 32; m <<= 1) {
        a0 += __shfl_xor(a0, m); a1 += __shfl_xor(a1, m);
        a2 += __shfl_xor(a2, m); a3 += __shfl_xor(a3, m);
        a4 += __shfl_xor(a4, m); a5 += __shfl_xor(a5, m);
        a6 += __shfl_xor(a6, m); a7 += __shfl_xor(a7, m);
    }
    if (lane < 16) {
        float dn = dis[n];
        uint4 u = *(const uint4*)(A2 + (long long)n * 128 + fg * 8);  // self (prescaled)
        const float4 bA = *(const float4*)&bias[fg * 8];
        const float4 bB = *(const float4*)&bias[fg * 8 + 4];
        float4 o0, o1;
        o0.x = fmaxf((a0 + bfl(u.x)) * dn + bA.x, 0.f);
        o0.y = fmaxf((a1 + bfh(u.x)) * dn + bA.y, 0.f);
        o0.z = fmaxf((a2 + bfl(u.y)) * dn + bA.z, 0.f);
        o0.w = fmaxf((a3 + bfh(u.y)) * dn + bA.w, 0.f);
        o1.x = fmaxf((a4 + bfl(u.z)) * dn + bB.x, 0.f);
        o1.y = fmaxf((a5 + bfh(u.z)) * dn + bB.y, 0.f);
        o1.z = fmaxf((a6 + bfl(u.w)) * dn + bB.z, 0.f);
        o1.w = fmaxf((a7 + bfh(u.w)) * dn + bB.w, 0.f);
        *(float4*)(outC + (long long)n * 128 + fg * 8)     = o0;
        *(float4*)(outC + (long long)n * 128 + fg * 8 + 4) = o1;
    }
}

// ---------------- Pool (batch sorted): 32-node strips, pre-reduced atomic flush -------

#define PSTRIP 32
__global__ __launch_bounds__(128) void gnn_pool(const float* __restrict__ h,
                                                const int* __restrict__ batch,
                                                const int* __restrict__ flags,
                                                float* __restrict__ pooled, int N, int B) {
    int i64 = flags[1];
    int f = threadIdx.x;
    int n0 = blockIdx.x * PSTRIP;
    if (n0 >= N) return;
    int nend = min(n0 + PSTRIP, N);
    int cur = clampi(ld_idx(batch, n0, i64), 0, B - 1);
    float acc = 0.0f;
    for (int n = n0; n < nend; ++n) {
        int b = clampi(ld_idx(batch, n, i64), 0, B - 1);
        if (b != cur) {
            atomicAdd(&pooled[cur * 128 + f], acc);
            acc = 0.0f; cur = b;
        }
        acc += h[(long long)n * 128 + f];
    }
    atomicAdd(&pooled[cur * 128 + f], acc);
}

// ---------------- head: mean (cnt via binary search) + MLP ----------------

__global__ __launch_bounds__(128) void gnn_head(const float* __restrict__ pooled,
                                                const int* __restrict__ batch,
                                                const float* __restrict__ W3,
                                                const float* __restrict__ b3,
                                                const float* __restrict__ W4,
                                                const float* __restrict__ b4,
                                                const int* __restrict__ flags,
                                                void* __restrict__ outv, int N) {
    __shared__ float xs[128];
    __shared__ float rs[128];
    __shared__ float cinv;
    int b = blockIdx.x, f = threadIdx.x;
    if (f == 0) {
        int i64 = flags[1];
        int L = 0, R = N;
        while (L < R) { int m = (L + R) >> 1; if (ld_idx(batch, m, i64) < b) L = m + 1; else R = m; }
        int lo = L;
        L = 0; R = N;
        while (L < R) { int m = (L + R) >> 1; if (ld_idx(batch, m, i64) < b + 1) L = m + 1; else R = m; }
        cinv = 1.0f / fmaxf((float)(L - lo), 1.0f);
    }
    __syncthreads();
    xs[f] = pooled[b * 128 + f] * cinv;
    __syncthreads();
    float acc = b3[f];
    for (int k = 0; k < 128; ++k) acc = fmaf(xs[k], W3[k * 128 + f], acc);
    rs[f] = fmaxf(acc, 0.f);
    __syncthreads();
    if (f < 64) {
        float a2 = b4[f];
        for (int k = 0; k < 128; ++k) a2 = fmaf(rs[k], W4[k * 64 + f], a2);
        if (flags[0]) ((float*)outv)[b * 64 + f] = a2;
        else          ((unsigned short*)outv)[b * 64 + f] = f2bf(a2);
    }
}

// ---------------- Launch ----------------

extern "C" void kernel_launch(void* const* d_in, const int* in_sizes, int n_in,
                              void* d_out, int out_size, void* d_ws, size_t ws_size,
                              hipStream_t stream) {
    const void* x  = d_in[0];
    const int* ei  = (const int*)d_in[1];
    const int* bat = (const int*)d_in[2];

    const int N = in_sizes[0] / 64;    // 50000
    const int E = in_sizes[1] / 2;     // 800000
    const int B = out_size / 64;       // 64
    const bool smalln = (N < 65536);

    char* p = (char*)d_ws;
    auto alloc = [&](size_t bytes) { void* q = (void*)p; p += (bytes + 255) & ~(size_t)255; return q; };
    int*   flags    = (int*)alloc(256);
    float* wsW      = (float*)alloc((size_t)OTOT * 4);
    int*   degcnt   = (int*)alloc((size_t)N * 4);
    float* dis      = (float*)alloc((size_t)N * 4);
    int*   excl     = (int*)alloc((size_t)N * 4);
    int*   bsums    = (int*)alloc(1024);
    int*   rank     = (int*)alloc((size_t)E * 4);
    void*  csr      = alloc((size_t)E * (smalln ? 2 : 4));
    unsigned short* xb = (unsigned short*)alloc((size_t)N * 64 * 2);
    float* H1       = (float*)alloc((size_t)N * 128 * 4);
    float* C2       = (float*)alloc((size_t)N * 128 * 4);
    unsigned short* A2 = (unsigned short*)alloc((size_t)N * 128 * 2);
    float* pooled   = (float*)alloc((size_t)B * 128 * 4);
    (void)ws_size; (void)n_in;

    const int nbN = (N + 255) / 256;   // 196 (fits single-block scan2)

    gnn_prep<<<512, 256, 0, stream>>>(d_in[3], d_in[4], d_in[5], d_in[6],
                                      d_in[7], d_in[8], d_in[9], d_in[10],
                                      ei, flags, degcnt, pooled, wsW, N, B);

    gnn_hist<<<(E + 1023) / 1024, 256, 0, stream>>>(ei, E, N, flags, degcnt, rank);
    gnn_scan1<<<nbN, 256, 0, stream>>>(degcnt, excl, bsums, dis, N);
    gnn_scan2<<<1, 256, 0, stream>>>(bsums, nbN);
    if (smalln)
        gnn_fill<true><<<(E + 255) / 256, 256, 0, stream>>>(ei, excl, bsums, rank, csr, E, N,
                                                            flags, x, dis, xb);
    else
        gnn_fill<false><<<(E + 255) / 256, 256, 0, stream>>>(ei, excl, bsums, rank, csr, E, N,
                                                             flags, x, dis, xb);

    const int nlin = (N + 15) / 16;    // 16-node blocks, 128 threads
    const int nagg = (N + 3) / 4;      // wave-per-node, 4 nodes / 256 threads

    // layer 1 (fused): H1 = relu((A_hat @ x) @ W1 + b1)
    if (smalln)
        gnn_aggx_lin1<true><<<nlin, 128, 0, stream>>>(xb, excl, bsums, csr, dis,
                                                      wsW + OW1, wsW + OB1, N, E, H1);
    else
        gnn_aggx_lin1<false><<<nlin, 128, 0, stream>>>(xb, excl, bsums, csr, dis,
                                                       wsW + OW1, wsW + OB1, N, E, H1);

    // layer 2: A2 = (H1 @ W2) * dis (bf16) ; C2 = relu(A_hat-partial @ A2 + b2)
    gnn_linear<128, false, true><<<nlin, 128, 0, stream>>>(H1, wsW + OW2, wsW + OB2, dis, N, (void*)A2);
    if (smalln)
        gnn_agg_bf<true><<<nagg, 256, 0, stream>>>(A2, excl, bsums, csr, dis, wsW + OB2, C2, N, E);
    else
        gnn_agg_bf<false><<<nagg, 256, 0, stream>>>(A2, excl, bsums, csr, dis, wsW + OB2, C2, N, E);

    // pool + head
    gnn_pool<<<(N + PSTRIP - 1) / PSTRIP, 128, 0, stream>>>(C2, bat, flags, pooled, N, B);
    gnn_head<<<B, 128, 0, stream>>>(pooled, bat, wsW + OW3, wsW + OB3,
                                    wsW + OW4, wsW + OB4, flags, d_out, N);
}

// Round 2
// 261.719 us; speedup vs baseline: 1.0646x; 1.0646x over previous
//
#include <hip/hip_runtime.h>

// ---------------- helpers ----------------

__device__ __forceinline__ float ldf(const void* p, long long i, int f32) {
    if (f32) return ((const float*)p)[i];
    unsigned int u = ((const unsigned short*)p)[i];
    return __uint_as_float(u << 16);
}
__device__ __forceinline__ float bfl(unsigned int u) { return __uint_as_float(u << 16); }
__device__ __forceinline__ float bfh(unsigned int u) { return __uint_as_float(u & 0xFFFF0000u); }
__device__ __forceinline__ int ld_idx(const int* p, long long i, int i64) {
    return i64 ? p[2 * i] : p[i];   // little-endian low word of int64
}
__device__ __forceinline__ unsigned short f2bf(float v) {
    unsigned int x = __float_as_uint(v);
    return (unsigned short)((x + 0x7FFFu + ((x >> 16) & 1u)) >> 16);  // RNE
}
__device__ __forceinline__ int clampi(int v, int lo, int hi) {
    return v < lo ? lo : (v > hi ? hi : v);
}

// ---------------- weights layout (contiguous f32) ----------------
#define OW1 0
#define OB1 8192
#define OW2 8320
#define OB2 24704
#define OW3 24832
#define OB3 41216
#define OW4 41344
#define OB4 49536
#define OTOT 49600

// ---------------- prep: dtype-detect + zero-init + weight convert ----------------
// flags[0]=1 f32 floats / 0 bf16 ; flags[1]=1 int64 / 0 int32

__global__ void gnn_prep(const void* W1, const void* b1, const void* W2, const void* b2,
                         const void* W3, const void* b3, const void* W4, const void* b4,
                         const int* __restrict__ ei,
                         int* __restrict__ flags_out,
                         int* __restrict__ degcnt, float* __restrict__ pooled,
                         float* __restrict__ wsW, int N, int B) {
    __shared__ int s_cnt, s_or;
    const int t = threadIdx.x;
    if (t == 0) { s_cnt = 0; s_or = 0; }
    __syncthreads();
    {
        const unsigned int* w1w = (const unsigned int*)W1;
        int c = 0, o = 0;
        for (int i = t; i < 512; i += 256) {
            unsigned int e = (w1w[i] >> 7) & 0xFFu;
            if (e >= 100 && e <= 140) c++;
        }
        for (int i = t; i < 1024; i += 256) o |= ei[2 * i + 1];
        atomicAdd(&s_cnt, c);
        atomicOr(&s_or, o);
    }
    __syncthreads();
    const int f32 = (s_cnt > 256) ? 0 : 1;
    if (blockIdx.x == 0 && t == 0) {
        flags_out[0] = f32;
        flags_out[1] = (s_or == 0) ? 1 : 0;
    }
    const int i = blockIdx.x * 256 + t;
    const int stride = gridDim.x * 256;
    for (int j = i; j < N; j += stride) degcnt[j] = 0;
    for (int j = i; j < B * 128; j += stride) pooled[j] = 0.f;
    for (int j = i; j < OTOT; j += stride) {
        float v;
        if      (j < OB1) v = ldf(W1, j - OW1, f32);
        else if (j < OW2) v = ldf(b1, j - OB1, f32);
        else if (j < OB2) v = ldf(W2, j - OW2, f32);
        else if (j < OW3) v = ldf(b2, j - OB2, f32);
        else if (j < OB3) v = ldf(W3, j - OW3, f32);
        else if (j < OW4) v = ldf(b3, j - OB3, f32);
        else if (j < OB4) v = ldf(W4, j - OW4, f32);
        else              v = ldf(b4, j - OB4, f32);
        wsW[j] = v;
    }
}

// ---------------- CSR build ----------------

__global__ void gnn_hist(const int* __restrict__ ei, int E, int N,
                         const int* __restrict__ flags, int* __restrict__ degcnt,
                         int* __restrict__ rank) {
    int base = (blockIdx.x * 256 + threadIdx.x) * 4;
    if (base >= E) return;
    int i64 = flags[1];
    int m = min(4, E - base);
    int d[4], r[4];
#pragma unroll
    for (int j = 0; j < 4; ++j)
        if (j < m) d[j] = clampi(ld_idx(ei, (long long)E + base + j, i64), 0, N - 1);
#pragma unroll
    for (int j = 0; j < 4; ++j)
        if (j < m) r[j] = atomicAdd(&degcnt[d[j]], 1);
#pragma unroll
    for (int j = 0; j < 4; ++j)
        if (j < m) rank[base + j] = r[j];
}

__global__ void gnn_scan1(const int* __restrict__ cnt, int* __restrict__ excl,
                          int* __restrict__ sums, float* __restrict__ dis, int N) {
    __shared__ int sh[256];
    int t = threadIdx.x;
    int i = blockIdx.x * 256 + t;
    int v = (i < N) ? cnt[i] : 0;
    sh[t] = v;
    __syncthreads();
    for (int off = 1; off < 256; off <<= 1) {
        int a = (t >= off) ? sh[t - off] : 0;
        __syncthreads();
        sh[t] += a;
        __syncthreads();
    }
    if (i < N) {
        excl[i] = sh[t] - v;
        dis[i] = rsqrtf((float)v + 1.0f);
    }
    if (t == 255) sums[blockIdx.x] = sh[255];
}

__global__ void gnn_scan2(int* __restrict__ sums, int nb) {
    __shared__ int sh[256];
    int t = threadIdx.x;
    int v = (t < nb) ? sums[t] : 0;
    sh[t] = v;
    __syncthreads();
    for (int off = 1; off < 256; off <<= 1) {
        int a = (t >= off) ? sh[t - off] : 0;
        __syncthreads();
        sh[t] += a;
        __syncthreads();
    }
    if (t < nb) sums[t] = sh[t] - v;
}

// fill: scatter src ids into CSR, and build dis-prescaled bf16 x table
//   xb[n][f] = bf16( x[n][f] * dis[n] )
template <bool SMALLN>
__global__ void gnn_fill(const int* __restrict__ ei, const int* __restrict__ excl,
                         const int* __restrict__ bsums, const int* __restrict__ rank,
                         void* __restrict__ csr, int E, int N,
                         const int* __restrict__ flags,
                         const void* __restrict__ x, const float* __restrict__ dis,
                         unsigned short* __restrict__ xb) {
    const int tid = blockIdx.x * 256 + threadIdx.x;
    const int i64 = flags[1];
    if (tid < E) {
        int s = clampi(ld_idx(ei, (long long)tid, i64), 0, N - 1);
        int d = clampi(ld_idx(ei, (long long)E + tid, i64), 0, N - 1);
        int pos = excl[d] + bsums[d >> 8] + rank[tid];
        if (SMALLN) ((unsigned short*)csr)[pos] = (unsigned short)s;
        else        ((int*)csr)[pos] = s;
    }
    const int f32 = flags[0];
    const int total = N * 16;                    // groups of 4 features
    const int stride = gridDim.x * 256;
    for (int j = tid; j < total; j += stride) {
        int n = j >> 4;
        float dn = dis[n];
        float v0, v1, v2, v3;
        if (f32) {
            float4 xv = ((const float4*)x)[j];
            v0 = xv.x; v1 = xv.y; v2 = xv.z; v3 = xv.w;
        } else {
            ushort4 xv = ((const ushort4*)x)[j];
            v0 = bfl(xv.x); v1 = bfl(xv.y); v2 = bfl(xv.z); v3 = bfl(xv.w);
        }
        ushort4 o;
        o.x = f2bf(v0 * dn); o.y = f2bf(v1 * dn);
        o.z = f2bf(v2 * dn); o.w = f2bf(v3 * dn);
        ((ushort4*)xb)[j] = o;
    }
}

template <bool SMALLN>
__device__ __forceinline__ int csr_at(const void* csr, int e) {
    return SMALLN ? (int)((const unsigned short*)csr)[e] : ((const int*)csr)[e];
}

// ---------------- fused layers 1+2a: agg(x) -> @W1+b1,relu -> @W2,*dis -> A2 (bf16) ----
// 16 nodes/block, 128 threads = 2 waves.
// Phase A: lane = (node 8/wave, fgroup 8) — serial shuffle-free edge loop, unroll 4.
// Phase B: Xs(16x64,pad68) @ W1 -> Hs (LDS).  Phase C: Hs @ W2 -> A2 (global, bf16).

template <bool SMALLN>
__global__ __launch_bounds__(128) void gnn_l1l2(const unsigned short* __restrict__ xb,
                                                const int* __restrict__ excl,
                                                const int* __restrict__ bsums,
                                                const void* __restrict__ csr,
                                                const float* __restrict__ dis,
                                                const float* __restrict__ W1,
                                                const float* __restrict__ b1,
                                                const float* __restrict__ W2,
                                                int N, int E,
                                                unsigned short* __restrict__ A2) {
    __shared__ float Xs[16 * 68];    // padded: 68 floats/row -> conflict-free stores
    __shared__ float Hs[16 * 128];
    const int t = threadIdx.x;
    const int nbase = blockIdx.x * 16;
    const int lane = t & 63;
    const int nd = (t >> 6) * 8 + (lane >> 3);   // node within block 0..15
    const int fg = lane & 7;                      // 8 bf16 features per lane
    const int n = nbase + nd;

    if (n < N) {
        const float dn = dis[n];
        uint4 us = *(const uint4*)(xb + (long long)n * 64 + fg * 8);  // self (prescaled)
        float a0 = bfl(us.x), a1 = bfh(us.x), a2 = bfl(us.y), a3 = bfh(us.y);
        float a4 = bfl(us.z), a5 = bfh(us.z), a6 = bfl(us.w), a7 = bfh(us.w);
        int beg = excl[n] + bsums[n >> 8];
        int end = (n + 1 < N) ? (excl[n + 1] + bsums[(n + 1) >> 8]) : E;
        int e = beg;
        for (; e + 4 <= end; e += 4) {
            int s0 = csr_at<SMALLN>(csr, e),     s1 = csr_at<SMALLN>(csr, e + 1);
            int s2 = csr_at<SMALLN>(csr, e + 2), s3 = csr_at<SMALLN>(csr, e + 3);
            uint4 u0 = *(const uint4*)(xb + (long long)s0 * 64 + fg * 8);
            uint4 u1 = *(const uint4*)(xb + (long long)s1 * 64 + fg * 8);
            uint4 u2 = *(const uint4*)(xb + (long long)s2 * 64 + fg * 8);
            uint4 u3 = *(const uint4*)(xb + (long long)s3 * 64 + fg * 8);
            a0 += bfl(u0.x); a1 += bfh(u0.x); a2 += bfl(u0.y); a3 += bfh(u0.y);
            a4 += bfl(u0.z); a5 += bfh(u0.z); a6 += bfl(u0.w); a7 += bfh(u0.w);
            a0 += bfl(u1.x); a1 += bfh(u1.x); a2 += bfl(u1.y); a3 += bfh(u1.y);
            a4 += bfl(u1.z); a5 += bfh(u1.z); a6 += bfl(u1.w); a7 += bfh(u1.w);
            a0 += bfl(u2.x); a1 += bfh(u2.x); a2 += bfl(u2.y); a3 += bfh(u2.y);
            a4 += bfl(u2.z); a5 += bfh(u2.z); a6 += bfl(u2.w); a7 += bfh(u2.w);
            a0 += bfl(u3.x); a1 += bfh(u3.x); a2 += bfl(u3.y); a3 += bfh(u3.y);
            a4 += bfl(u3.z); a5 += bfh(u3.z); a6 += bfl(u3.w); a7 += bfh(u3.w);
        }
        for (; e < end; ++e) {
            int s = csr_at<SMALLN>(csr, e);
            uint4 u = *(const uint4*)(xb + (long long)s * 64 + fg * 8);
            a0 += bfl(u.x); a1 += bfh(u.x); a2 += bfl(u.y); a3 += bfh(u.y);
            a4 += bfl(u.z); a5 += bfh(u.z); a6 += bfl(u.w); a7 += bfh(u.w);
        }
        float4 o0, o1;
        o0.x = a0 * dn; o0.y = a1 * dn; o0.z = a2 * dn; o0.w = a3 * dn;
        o1.x = a4 * dn; o1.y = a5 * dn; o1.z = a6 * dn; o1.w = a7 * dn;
        *(float4*)&Xs[nd * 68 + fg * 8]     = o0;
        *(float4*)&Xs[nd * 68 + fg * 8 + 4] = o1;
    } else {
        float4 z = make_float4(0.f, 0.f, 0.f, 0.f);
        *(float4*)&Xs[nd * 68 + fg * 8]     = z;
        *(float4*)&Xs[nd * 68 + fg * 8 + 4] = z;
    }
    __syncthreads();

    const int fgB = t & 31, ng = t >> 5;          // ng 0..3 -> nodes ng*4..ng*4+3
    const int f0 = fgB * 4, n0 = ng * 4;
    // Phase B: Hs = relu(Xs @ W1 + b1)
    {
        const float4* Wp = (const float4*)W1;     // [k][32]
        float4 acc[4];
#pragma unroll
        for (int j = 0; j < 4; ++j) acc[j] = make_float4(0.f, 0.f, 0.f, 0.f);
#pragma unroll 4
        for (int k4 = 0; k4 < 16; ++k4) {
            const float4 wa = Wp[(4 * k4 + 0) * 32 + fgB];
            const float4 wb = Wp[(4 * k4 + 1) * 32 + fgB];
            const float4 wc = Wp[(4 * k4 + 2) * 32 + fgB];
            const float4 wd = Wp[(4 * k4 + 3) * 32 + fgB];
#pragma unroll
            for (int j = 0; j < 4; ++j) {
                const float4 xv = *(const float4*)&Xs[(n0 + j) * 68 + k4 * 4];
                acc[j].x = fmaf(xv.x, wa.x, acc[j].x); acc[j].y = fmaf(xv.x, wa.y, acc[j].y);
                acc[j].z = fmaf(xv.x, wa.z, acc[j].z); acc[j].w = fmaf(xv.x, wa.w, acc[j].w);
                acc[j].x = fmaf(xv.y, wb.x, acc[j].x); acc[j].y = fmaf(xv.y, wb.y, acc[j].y);
                acc[j].z = fmaf(xv.y, wb.z, acc[j].z); acc[j].w = fmaf(xv.y, wb.w, acc[j].w);
                acc[j].x = fmaf(xv.z, wc.x, acc[j].x); acc[j].y = fmaf(xv.z, wc.y, acc[j].y);
                acc[j].z = fmaf(xv.z, wc.z, acc[j].z); acc[j].w = fmaf(xv.z, wc.w, acc[j].w);
                acc[j].x = fmaf(xv.w, wd.x, acc[j].x); acc[j].y = fmaf(xv.w, wd.y, acc[j].y);
                acc[j].z = fmaf(xv.w, wd.z, acc[j].z); acc[j].w = fmaf(xv.w, wd.w, acc[j].w);
            }
        }
        const float4 b = *(const float4*)&b1[f0];
#pragma unroll
        for (int j = 0; j < 4; ++j) {
            float4 a = acc[j];
            a.x = fmaxf(a.x + b.x, 0.f);
            a.y = fmaxf(a.y + b.y, 0.f);
            a.z = fmaxf(a.z + b.z, 0.f);
            a.w = fmaxf(a.w + b.w, 0.f);
            *(float4*)&Hs[(n0 + j) * 128 + f0] = a;
        }
    }
    __syncthreads();
    // Phase C: A2 = bf16((Hs @ W2) * dis)
    {
        const float4* Wp = (const float4*)W2;     // [k][32]
        float4 acc[4];
#pragma unroll
        for (int j = 0; j < 4; ++j) acc[j] = make_float4(0.f, 0.f, 0.f, 0.f);
#pragma unroll 4
        for (int k4 = 0; k4 < 32; ++k4) {
            const float4 wa = Wp[(4 * k4 + 0) * 32 + fgB];
            const float4 wb = Wp[(4 * k4 + 1) * 32 + fgB];
            const float4 wc = Wp[(4 * k4 + 2) * 32 + fgB];
            const float4 wd = Wp[(4 * k4 + 3) * 32 + fgB];
#pragma unroll
            for (int j = 0; j < 4; ++j) {
                const float4 xv = *(const float4*)&Hs[(n0 + j) * 128 + k4 * 4];
                acc[j].x = fmaf(xv.x, wa.x, acc[j].x); acc[j].y = fmaf(xv.x, wa.y, acc[j].y);
                acc[j].z = fmaf(xv.x, wa.z, acc[j].z); acc[j].w = fmaf(xv.x, wa.w, acc[j].w);
                acc[j].x = fmaf(xv.y, wb.x, acc[j].x); acc[j].y = fmaf(xv.y, wb.y, acc[j].y);
                acc[j].z = fmaf(xv.y, wb.z, acc[j].z); acc[j].w = fmaf(xv.y, wb.w, acc[j].w);
                acc[j].x = fmaf(xv.z, wc.x, acc[j].x); acc[j].y = fmaf(xv.z, wc.y, acc[j].y);
                acc[j].z = fmaf(xv.z, wc.z, acc[j].z); acc[j].w = fmaf(xv.z, wc.w, acc[j].w);
                acc[j].x = fmaf(xv.w, wd.x, acc[j].x); acc[j].y = fmaf(xv.w, wd.y, acc[j].y);
                acc[j].z = fmaf(xv.w, wd.z, acc[j].z); acc[j].w = fmaf(xv.w, wd.w, acc[j].w);
            }
        }
#pragma unroll
        for (int j = 0; j < 4; ++j) {
            int nn = nbase + n0 + j;
            if (nn >= N) continue;
            const float dn = dis[nn];
            float4 a = acc[j];
            a.x *= dn; a.y *= dn; a.z *= dn; a.w *= dn;
            uint2 u;
            u.x = (unsigned int)f2bf(a.x) | ((unsigned int)f2bf(a.y) << 16);
            u.y = (unsigned int)f2bf(a.z) | ((unsigned int)f2bf(a.w) << 16);
            *(uint2*)(A2 + (long long)nn * 128 + f0) = u;
        }
    }
}

// ---------------- Layer-2 aggregation over prescaled bf16 rows -> C2 (f32) -------------
// Shuffle-free: lane = (node 4/wave, fgroup 16). Serial edge loop, unroll 4.

template <bool SMALLN>
__global__ __launch_bounds__(256) void gnn_agg_bf(const unsigned short* __restrict__ A2,
                                                  const int* __restrict__ excl,
                                                  const int* __restrict__ bsums,
                                                  const void* __restrict__ csr,
                                                  const float* __restrict__ dis,
                                                  const float* __restrict__ bias,
                                                  float* __restrict__ outC, int N, int E) {
    const int t = threadIdx.x;
    const int lane = t & 63;
    const int n = blockIdx.x * 16 + (t >> 6) * 4 + (lane >> 4);
    if (n >= N) return;
    const int fg = lane & 15;          // uint4 = 8 bf16 each
    const float dn = dis[n];
    uint4 us = *(const uint4*)(A2 + (long long)n * 128 + fg * 8);  // self (prescaled)
    float a0 = bfl(us.x), a1 = bfh(us.x), a2 = bfl(us.y), a3 = bfh(us.y);
    float a4 = bfl(us.z), a5 = bfh(us.z), a6 = bfl(us.w), a7 = bfh(us.w);
    int beg = excl[n] + bsums[n >> 8];
    int end = (n + 1 < N) ? (excl[n + 1] + bsums[(n + 1) >> 8]) : E;
    int e = beg;
    for (; e + 4 <= end; e += 4) {
        int s0 = csr_at<SMALLN>(csr, e),     s1 = csr_at<SMALLN>(csr, e + 1);
        int s2 = csr_at<SMALLN>(csr, e + 2), s3 = csr_at<SMALLN>(csr, e + 3);
        uint4 u0 = *(const uint4*)(A2 + (long long)s0 * 128 + fg * 8);
        uint4 u1 = *(const uint4*)(A2 + (long long)s1 * 128 + fg * 8);
        uint4 u2 = *(const uint4*)(A2 + (long long)s2 * 128 + fg * 8);
        uint4 u3 = *(const uint4*)(A2 + (long long)s3 * 128 + fg * 8);
        a0 += bfl(u0.x); a1 += bfh(u0.x); a2 += bfl(u0.y); a3 += bfh(u0.y);
        a4 += bfl(u0.z); a5 += bfh(u0.z); a6 += bfl(u0.w); a7 += bfh(u0.w);
        a0 += bfl(u1.x); a1 += bfh(u1.x); a2 += bfl(u1.y); a3 += bfh(u1.y);
        a4 += bfl(u1.z); a5 += bfh(u1.z); a6 += bfl(u1.w); a7 += bfh(u1.w);
        a0 += bfl(u2.x); a1 += bfh(u2.x); a2 += bfl(u2.y); a3 += bfh(u2.y);
        a4 += bfl(u2.z); a5 += bfh(u2.z); a6 += bfl(u2.w); a7 += bfh(u2.w);
        a0 += bfl(u3.x); a1 += bfh(u3.x); a2 += bfl(u3.y); a3 += bfh(u3.y);
        a4 += bfl(u3.z); a5 += bfh(u3.z); a6 += bfl(u3.w); a7 += bfh(u3.w);
    }
    for (; e < end; ++e) {
        int s = csr_at<SMALLN>(csr, e);
        uint4 u = *(const uint4*)(A2 + (long long)s * 128 + fg * 8);
        a0 += bfl(u.x); a1 += bfh(u.x); a2 += bfl(u.y); a3 += bfh(u.y);
        a4 += bfl(u.z); a5 += bfh(u.z); a6 += bfl(u.w); a7 += bfh(u.w);
    }
    const float4 bA = *(const float4*)&bias[fg * 8];
    const float4 bB = *(const float4*)&bias[fg * 8 + 4];
    float4 o0, o1;
    o0.x = fmaxf(a0 * dn + bA.x, 0.f);
    o0.y = fmaxf(a1 * dn + bA.y, 0.f);
    o0.z = fmaxf(a2 * dn + bA.z, 0.f);
    o0.w = fmaxf(a3 * dn + bA.w, 0.f);
    o1.x = fmaxf(a4 * dn + bB.x, 0.f);
    o1.y = fmaxf(a5 * dn + bB.y, 0.f);
    o1.z = fmaxf(a6 * dn + bB.z, 0.f);
    o1.w = fmaxf(a7 * dn + bB.w, 0.f);
    *(float4*)(outC + (long long)n * 128 + fg * 8)     = o0;
    *(float4*)(outC + (long long)n * 128 + fg * 8 + 4) = o1;
}

// ---------------- Pool (batch sorted): 32-node strips, pre-reduced atomic flush -------

#define PSTRIP 32
__global__ __launch_bounds__(128) void gnn_pool(const float* __restrict__ h,
                                                const int* __restrict__ batch,
                                                const int* __restrict__ flags,
                                                float* __restrict__ pooled, int N, int B) {
    int i64 = flags[1];
    int f = threadIdx.x;
    int n0 = blockIdx.x * PSTRIP;
    if (n0 >= N) return;
    int nend = min(n0 + PSTRIP, N);
    int cur = clampi(ld_idx(batch, n0, i64), 0, B - 1);
    float acc = 0.0f;
    for (int n = n0; n < nend; ++n) {
        int b = clampi(ld_idx(batch, n, i64), 0, B - 1);
        if (b != cur) {
            atomicAdd(&pooled[cur * 128 + f], acc);
            acc = 0.0f; cur = b;
        }
        acc += h[(long long)n * 128 + f];
    }
    atomicAdd(&pooled[cur * 128 + f], acc);
}

// ---------------- head: mean (cnt via binary search) + MLP ----------------

__global__ __launch_bounds__(128) void gnn_head(const float* __restrict__ pooled,
                                                const int* __restrict__ batch,
                                                const float* __restrict__ W3,
                                                const float* __restrict__ b3,
                                                const float* __restrict__ W4,
                                                const float* __restrict__ b4,
                                                const int* __restrict__ flags,
                                                void* __restrict__ outv, int N) {
    __shared__ float xs[128];
    __shared__ float rs[128];
    __shared__ float cinv;
    int b = blockIdx.x, f = threadIdx.x;
    if (f == 0) {
        int i64 = flags[1];
        int L = 0, R = N;
        while (L < R) { int m = (L + R) >> 1; if (ld_idx(batch, m, i64) < b) L = m + 1; else R = m; }
        int lo = L;
        L = 0; R = N;
        while (L < R) { int m = (L + R) >> 1; if (ld_idx(batch, m, i64) < b + 1) L = m + 1; else R = m; }
        cinv = 1.0f / fmaxf((float)(L - lo), 1.0f);
    }
    __syncthreads();
    xs[f] = pooled[b * 128 + f] * cinv;
    __syncthreads();
    float acc = b3[f];
    for (int k = 0; k < 128; ++k) acc = fmaf(xs[k], W3[k * 128 + f], acc);
    rs[f] = fmaxf(acc, 0.f);
    __syncthreads();
    if (f < 64) {
        float a2 = b4[f];
        for (int k = 0; k < 128; ++k) a2 = fmaf(rs[k], W4[k * 64 + f], a2);
        if (flags[0]) ((float*)outv)[b * 64 + f] = a2;
        else          ((unsigned short*)outv)[b * 64 + f] = f2bf(a2);
    }
}

// ---------------- Launch ----------------

extern "C" void kernel_launch(void* const* d_in, const int* in_sizes, int n_in,
                              void* d_out, int out_size, void* d_ws, size_t ws_size,
                              hipStream_t stream) {
    const void* x  = d_in[0];
    const int* ei  = (const int*)d_in[1];
    const int* bat = (const int*)d_in[2];

    const int N = in_sizes[0] / 64;    // 50000
    const int E = in_sizes[1] / 2;     // 800000
    const int B = out_size / 64;       // 64
    const bool smalln = (N < 65536);

    char* p = (char*)d_ws;
    auto alloc = [&](size_t bytes) { void* q = (void*)p; p += (bytes + 255) & ~(size_t)255; return q; };
    int*   flags    = (int*)alloc(256);
    float* wsW      = (float*)alloc((size_t)OTOT * 4);
    int*   degcnt   = (int*)alloc((size_t)N * 4);
    float* dis      = (float*)alloc((size_t)N * 4);
    int*   excl     = (int*)alloc((size_t)N * 4);
    int*   bsums    = (int*)alloc(1024);
    int*   rank     = (int*)alloc((size_t)E * 4);
    void*  csr      = alloc((size_t)E * (smalln ? 2 : 4));
    unsigned short* xb = (unsigned short*)alloc((size_t)N * 64 * 2);
    float* C2       = (float*)alloc((size_t)N * 128 * 4);
    unsigned short* A2 = (unsigned short*)alloc((size_t)N * 128 * 2);
    float* pooled   = (float*)alloc((size_t)B * 128 * 4);
    (void)ws_size; (void)n_in;

    const int nbN = (N + 255) / 256;   // 196 (fits single-block scan2)

    gnn_prep<<<512, 256, 0, stream>>>(d_in[3], d_in[4], d_in[5], d_in[6],
                                      d_in[7], d_in[8], d_in[9], d_in[10],
                                      ei, flags, degcnt, pooled, wsW, N, B);

    gnn_hist<<<(E + 1023) / 1024, 256, 0, stream>>>(ei, E, N, flags, degcnt, rank);
    gnn_scan1<<<nbN, 256, 0, stream>>>(degcnt, excl, bsums, dis, N);
    gnn_scan2<<<1, 256, 0, stream>>>(bsums, nbN);
    if (smalln)
        gnn_fill<true><<<(E + 255) / 256, 256, 0, stream>>>(ei, excl, bsums, rank, csr, E, N,
                                                            flags, x, dis, xb);
    else
        gnn_fill<false><<<(E + 255) / 256, 256, 0, stream>>>(ei, excl, bsums, rank, csr, E, N,
                                                             flags, x, dis, xb);

    const int nblk = (N + 15) / 16;    // 16-node blocks

    // fused layers 1+2a: A2 = bf16( (relu((A_hat@x)@W1+b1)) @ W2 * dis )
    if (smalln)
        gnn_l1l2<true><<<nblk, 128, 0, stream>>>(xb, excl, bsums, csr, dis,
                                                 wsW + OW1, wsW + OB1, wsW + OW2, N, E, A2);
    else
        gnn_l1l2<false><<<nblk, 128, 0, stream>>>(xb, excl, bsums, csr, dis,
                                                  wsW + OW1, wsW + OB1, wsW + OW2, N, E, A2);

    // layer 2b: C2 = relu(A_hat-agg(A2) * dis + b2)
    if (smalln)
        gnn_agg_bf<true><<<nblk, 256, 0, stream>>>(A2, excl, bsums, csr, dis, wsW + OB2, C2, N, E);
    else
        gnn_agg_bf<false><<<nblk, 256, 0, stream>>>(A2, excl, bsums, csr, dis, wsW + OB2, C2, N, E);

    // pool + head
    gnn_pool<<<(N + PSTRIP - 1) / PSTRIP, 128, 0, stream>>>(C2, bat, flags, pooled, N, B);
    gnn_head<<<B, 128, 0, stream>>>(pooled, bat, wsW + OW3, wsW + OB3,
                                    wsW + OW4, wsW + OB4, flags, d_out, N);
}